// Round 13
// baseline (273.795 us; speedup 1.0000x reference)
//
#include <hip/hip_runtime.h>
#include <hip/hip_bf16.h>

#define NEDGE 800000
#define NNODE 50000
#define NBATCH (NEDGE / 128)   // 6250 batches of 128 edges (8 waves x 16 edges)

typedef __attribute__((ext_vector_type(8))) short bf16x8;
typedef __attribute__((ext_vector_type(4))) float f32x4;
typedef __attribute__((ext_vector_type(4))) float f4;

static __device__ __forceinline__ unsigned short f2bf(float f) {
    union { float f; unsigned u; } v; v.f = f;
    unsigned r = v.u + 0x7fffu + ((v.u >> 16) & 1u);   // RNE
    return (unsigned short)(r >> 16);
}

// DPP-based sum allreduce over each 16-lane quarter (DPP "row" = 16 lanes).
template<int CTRL>
static __device__ __forceinline__ float dppadd(float x) {
    int y = __builtin_amdgcn_update_dpp(0, __builtin_bit_cast(int, x), CTRL, 0xf, 0xf, true);
    return x + __builtin_bit_cast(float, y);
}
static __device__ __forceinline__ float allred16(float x) {
    x = dppadd<0xB1>(x);    // quad_perm xor1
    x = dppadd<0x4E>(x);    // quad_perm xor2
    x = dppadd<0x141>(x);   // row_half_mirror
    x = dppadd<0x140>(x);   // row_mirror
    return x;
}

static __device__ __forceinline__ unsigned cvt_pk_bf16(float lo, float hi) {
    unsigned r;
    asm("v_cvt_pk_bf16_f32 %0, %1, %2" : "=v"(r) : "v"(lo), "v"(hi));
    return r;
}
// raw 2^x (scores pre-scaled by log2e folded into Wq/bq); |x| < ~16 here
static __device__ __forceinline__ float fexp2(float x) {
    float r; asm("v_exp_f32 %0, %1" : "=v"(r) : "v"(x)); return r;
}

// LESSON (R9): Wo CANNOT fold into Wv — multi-head (H=4,D=16) attn weights
// depend on head index, Wo@Wv mixes heads. obuf + phase-3 Wo MFMA stays.
// LESSON (R11): char*-reinterpret f4 loads with hand-folded byte offsets
// failed correctness — keep plain indexed addressing.
// Occupancy (R2-R12, closed): 16 waves/CU, register-capped (unified
// VGPR+AGPR ~124/wave); 512-thr blocks quantize to {8,16,24} waves and 24
// needs <=85 regs (spills, R3); 256-thr blocks hit the LDS wall. Structural.
// R13: Q-tile — one extra A-fragment whose 16 rows are the token-0 rows
// (= LN(x_cen)) of all 16 edges, row r -> edge (r&3)*4+(r>>2). Then
// aqT[m] at lane (qg,rt) = q[edge m*4+qg][nt*16+rt]: 8 Q-MFMAs replace 32.
__global__ __launch_bounds__(512, 4) void nti_main(
    const float* __restrict__ x_cen, const float* __restrict__ x_nei,
    const int* __restrict__ eidx,
    const float* __restrict__ ln_g, const float* __restrict__ ln_b,
    const float* __restrict__ Wq, const float* __restrict__ bq,
    const float* __restrict__ Wk, const float* __restrict__ bk,
    const float* __restrict__ Wv, const float* __restrict__ bv,
    const float* __restrict__ Wo, const float* __restrict__ bo,
    float* __restrict__ outsum, float* __restrict__ cnt)
{
    // B-fragments: [mat*8 + kh*4 + nt][lane][8 bf16]  (q=0,k=1,v=2,o=3)
    __shared__ __align__(16) unsigned short wfrag[32][64][8];   // 32 KB
    __shared__ float bias_s[4][64];                             // 1 KB
    // per-wave O tile: 16 rows (edges) x 64 cols, pad to 72 (row = 144B)
    __shared__ __align__(16) unsigned short obuf[8][16][72];    // 18 KB

    const int tid = threadIdx.x;

    // ---- one-time weight staging: fold LN affine into Wq/Wk/Wv; fold
    // D^-0.5 * log2(e) into Wq/bq so softmax uses raw v_exp_f32 (2^x) ----
    if (tid < 256) {
        const int mat = tid >> 6, c = tid & 63;
        const float* W  = (mat == 0) ? Wq : (mat == 1) ? Wk : (mat == 2) ? Wv : Wo;
        const float* bb = (mat == 0) ? bq : (mat == 1) ? bk : (mat == 2) ? bv : bo;
        const float qs = (mat == 0) ? 0.25f * 1.44269504f : 1.0f;
        float bias = bb[c];
        for (int j = 0; j < 64; ++j) {
            float w = W[c * 64 + j];
            if (mat < 3) { bias += ln_b[j] * w; w *= ln_g[j]; }
            const int kh = j >> 5, ln = ((j >> 3) & 3) * 16 + (c & 15), i = j & 7;
            wfrag[mat * 8 + kh * 4 + (c >> 4)][ln][i] = f2bf(w * qs);
        }
        bias_s[mat][c] = bias * qs;
    }
    __syncthreads();

    const int wid = tid >> 6, lane = tid & 63;
    const int qg = lane >> 4;        // quarter / k-chunk
    const int rt = lane & 15;        // row within M-tile
    const int tok = rt & 3;          // token type of this row
    const int em  = rt >> 2;         // edge within M-tile
    const float ac = (tok == 0 || tok == 2) ? 1.f : (tok == 3) ? -1.f : 0.f;
    const float an = (tok == 0) ? 0.f : 1.f;

    // loop-invariant biases -> registers (bk dropped: softmax shift-invariant;
    // bv post-added since sum attn = 1; bo folded into residual add)
    float biasq[4], biasv[4], biaso[4];
    #pragma unroll
    for (int nt = 0; nt < 4; ++nt) {
        biasq[nt] = bias_s[0][nt * 16 + rt];
        biasv[nt] = bias_s[2][nt * 16 + rt];
        biaso[nt] = bias_s[3][nt * 16 + rt];
    }
    const f32x4 vzero = {0.f, 0.f, 0.f, 0.f};   // persistent zero C operand

    for (int batch = blockIdx.x; batch < NBATCH; batch += gridDim.x) {
        const int ebase = batch * 128 + wid * 16;

        // prefetch scatter targets early; pre-multiplied byte-offset bases so
        // epilogue atomics use base + imm-foldable nt*16
        int tg[4], tgb[4];
        #pragma unroll
        for (int r = 0; r < 4; ++r) {
            tg[r]  = eidx[NEDGE + ebase + qg * 4 + r];
            tgb[r] = tg[r] * 64 + rt;
        }

        // ---- phase 1: build A-fragments (LN'd tokens) for 4 M-tiles = 16 edges ----
        bf16x8 af[4][2];
        #pragma unroll
        for (int m = 0; m < 4; ++m) {
            const int eg = ebase + m * 4 + em;            // int32 offsets throughout
            const f4* pc4 = (const f4*)(x_cen + eg * 64);
            const f4* pn4 = (const f4*)(x_nei + eg * 64);
            f4 a0 = pc4[qg * 2], a1 = pc4[qg * 2 + 1], a2 = pc4[8 + qg * 2], a3 = pc4[8 + qg * 2 + 1];
            f4 b0 = pn4[qg * 2], b1 = pn4[qg * 2 + 1], b2 = pn4[8 + qg * 2], b3 = pn4[8 + qg * 2 + 1];
            float tv[16];
            #pragma unroll
            for (int i = 0; i < 4; ++i) {
                tv[i]      = ac * a0[i] + an * b0[i];
                tv[4 + i]  = ac * a1[i] + an * b1[i];
                tv[8 + i]  = ac * a2[i] + an * b2[i];
                tv[12 + i] = ac * a3[i] + an * b3[i];
            }
            float s = 0.f, ss = 0.f;
            #pragma unroll
            for (int i = 0; i < 16; ++i) { s += tv[i]; ss = fmaf(tv[i], tv[i], ss); }
            s  += __shfl_xor(s, 16, 64);  ss += __shfl_xor(ss, 16, 64);
            s  += __shfl_xor(s, 32, 64);  ss += __shfl_xor(ss, 32, 64);
            const float mu  = s * 0.015625f;
            const float var = fmaf(ss, 0.015625f, -mu * mu);
            const float rs  = rsqrtf(var + 1e-5f);
            const float nmrs = -mu * rs;
            #pragma unroll
            for (int kh = 0; kh < 2; ++kh) {
                union { bf16x8 v; unsigned u[4]; } pk;
                #pragma unroll
                for (int p = 0; p < 4; ++p) {
                    float lo = fmaf(tv[kh * 8 + 2 * p],     rs, nmrs);
                    float hi = fmaf(tv[kh * 8 + 2 * p + 1], rs, nmrs);
                    pk.u[p] = cvt_pk_bf16(lo, hi);
                }
                af[m][kh] = pk.v;
            }
        }

        // ---- Q-tile: rows = token-0 (= LN(x_cen)) of 16 edges, permuted so
        // D row qg*4+m = edge m*4+qg. Lane (qg,rt) supplies A row rt =
        // LN(x_cen[ebase + (rt&3)*4 + (rt>>2)]), k-cols qg*8+i / 32+qg*8+i.
        bf16x8 afq[2];
        {
            const int eq = ebase + (rt & 3) * 4 + (rt >> 2);
            const f4* pq = (const f4*)(x_cen + eq * 64);
            f4 a0 = pq[qg * 2], a1 = pq[qg * 2 + 1], a2 = pq[8 + qg * 2], a3 = pq[8 + qg * 2 + 1];
            float tq[16];
            #pragma unroll
            for (int i = 0; i < 4; ++i) {
                tq[i] = a0[i]; tq[4 + i] = a1[i]; tq[8 + i] = a2[i]; tq[12 + i] = a3[i];
            }
            float s = 0.f, ss = 0.f;
            #pragma unroll
            for (int i = 0; i < 16; ++i) { s += tq[i]; ss = fmaf(tq[i], tq[i], ss); }
            s  += __shfl_xor(s, 16, 64);  ss += __shfl_xor(ss, 16, 64);
            s  += __shfl_xor(s, 32, 64);  ss += __shfl_xor(ss, 32, 64);
            const float mu  = s * 0.015625f;
            const float var = fmaf(ss, 0.015625f, -mu * mu);
            const float rs  = rsqrtf(var + 1e-5f);
            const float nmrs = -mu * rs;
            #pragma unroll
            for (int kh = 0; kh < 2; ++kh) {
                union { bf16x8 v; unsigned u[4]; } pk;
                #pragma unroll
                for (int p = 0; p < 4; ++p) {
                    float lo = fmaf(tq[kh * 8 + 2 * p],     rs, nmrs);
                    float hi = fmaf(tq[kh * 8 + 2 * p + 1], rs, nmrs);
                    pk.u[p] = cvt_pk_bf16(lo, hi);
                }
                afq[kh] = pk.v;
            }
        }

        __builtin_amdgcn_s_setprio(1);   // MFMA/VALU-dense region; waves independent

        // ---- phase 2: per head nt: q (once) + per-m k/v proj + softmax + PV ----
        #pragma unroll
        for (int nt = 0; nt < 4; ++nt) {
            bf16x8 wq0 = *(const bf16x8*)&wfrag[0  + nt][lane][0];
            bf16x8 wq1 = *(const bf16x8*)&wfrag[4  + nt][lane][0];
            bf16x8 wk0 = *(const bf16x8*)&wfrag[8  + nt][lane][0];
            bf16x8 wk1 = *(const bf16x8*)&wfrag[12 + nt][lane][0];
            bf16x8 wv0 = *(const bf16x8*)&wfrag[16 + nt][lane][0];
            bf16x8 wv1 = *(const bf16x8*)&wfrag[20 + nt][lane][0];
            // Q for all 16 edges of this head in 2 MFMAs:
            // aqT[m] = q[edge m*4+qg][nt*16+rt] at lane (qg,rt)
            f32x4 aqT = __builtin_amdgcn_mfma_f32_16x16x32_bf16(afq[0], wq0, vzero, 0, 0, 0);
            aqT = __builtin_amdgcn_mfma_f32_16x16x32_bf16(afq[1], wq1, aqT, 0, 0, 0);
            #pragma unroll
            for (int m = 0; m < 4; ++m) {
                f32x4 ak = __builtin_amdgcn_mfma_f32_16x16x32_bf16(af[m][0], wk0, vzero, 0, 0, 0);
                ak = __builtin_amdgcn_mfma_f32_16x16x32_bf16(af[m][1], wk1, ak, 0, 0, 0);
                f32x4 av = __builtin_amdgcn_mfma_f32_16x16x32_bf16(af[m][0], wv0, vzero, 0, 0, 0);
                av = __builtin_amdgcn_mfma_f32_16x16x32_bf16(af[m][1], wv1, av, 0, 0, 0);
                // scores: q dot k rows over this head's 16 dims (rt lanes of qg)
                const float q0 = aqT[m] + biasq[nt];
                float p0 = allred16(q0 * ak[0]);
                float p1 = allred16(q0 * ak[1]);
                float p2 = allred16(q0 * ak[2]);
                float p3 = allred16(q0 * ak[3]);
                // softmax: no max-sub (|p| bounded); log2e pre-folded -> raw 2^x
                const float e0 = fexp2(p0), e1 = fexp2(p1);
                const float e2 = fexp2(p2), e3 = fexp2(p3);
                const float inv = __builtin_amdgcn_rcpf(e0 + e1 + e2 + e3);
                const float dot = e0 * av[0] + e1 * av[1] + e2 * av[2] + e3 * av[3];
                const float ov = fmaf(dot, inv, biasv[nt]);   // bv post-add (sum attn = 1)
                obuf[wid][m * 4 + qg][nt * 16 + rt] = (unsigned short)cvt_pk_bf16(ov, ov);
            }
        }
        // no __syncthreads: obuf is per-wave; same-wave LDS RAW is lgkmcnt-ordered

        // ---- residual prefetch (+bo fold): overlap L2 latency with phase-3 ----
        float res[4][4];
        #pragma unroll
        for (int nt = 0; nt < 4; ++nt) {
            const int col = nt * 16 + rt;
            #pragma unroll
            for (int r = 0; r < 4; ++r)
                res[nt][r] = x_cen[(ebase + qg * 4 + r) * 64 + col] + biaso[nt];
        }

        // ---- phase 3: Wo projection (all 16 rows = 16 edges valid) ----
        bf16x8 oa0 = *(const bf16x8*)&obuf[wid][rt][qg * 8];
        bf16x8 oa1 = *(const bf16x8*)&obuf[wid][rt][32 + qg * 8];
        f32x4 accO[4];
        #pragma unroll
        for (int nt = 0; nt < 4; ++nt) {
            bf16x8 wo0 = *(const bf16x8*)&wfrag[24 + nt][lane][0];
            bf16x8 wo1 = *(const bf16x8*)&wfrag[28 + nt][lane][0];
            f32x4 acc = __builtin_amdgcn_mfma_f32_16x16x32_bf16(oa0, wo0, vzero, 0, 0, 0);
            acc = __builtin_amdgcn_mfma_f32_16x16x32_bf16(oa1, wo1, acc, 0, 0, 0);
            accO[nt] = acc;
        }
        __builtin_amdgcn_s_setprio(0);

        // ---- epilogue: residual + scatter-add (all 64 lanes active) ----
        #pragma unroll
        for (int nt = 0; nt < 4; ++nt) {
            #pragma unroll
            for (int r = 0; r < 4; ++r) {
                const float val = accO[nt][r] + res[nt][r];
                atomicAdd(outsum + tgb[r] + nt * 16, val);
            }
        }
        if (rt == 0) {
            #pragma unroll
            for (int r = 0; r < 4; ++r) atomicAdd(cnt + tg[r], 1.0f);
        }
    }
}

__global__ void nti_div(float* __restrict__ out, const float* __restrict__ cnt) {
    int i = blockIdx.x * 256 + threadIdx.x;
    if (i < NNODE * 64) {
        float c = cnt[i >> 6];
        out[i] = out[i] / fmaxf(c, 1.0f);
    }
}

extern "C" void kernel_launch(void* const* d_in, const int* in_sizes, int n_in,
                              void* d_out, int out_size, void* d_ws, size_t ws_size,
                              hipStream_t stream) {
    const float* x_cen = (const float*)d_in[0];
    const float* x_nei = (const float*)d_in[1];
    const int*   eidx  = (const int*)d_in[2];
    const float* ln_g  = (const float*)d_in[3];
    const float* ln_b  = (const float*)d_in[4];
    const float* Wq = (const float*)d_in[5];  const float* bq = (const float*)d_in[6];
    const float* Wk = (const float*)d_in[7];  const float* bk = (const float*)d_in[8];
    const float* Wv = (const float*)d_in[9];  const float* bv = (const float*)d_in[10];
    const float* Wo = (const float*)d_in[11]; const float* bo = (const float*)d_in[12];
    float* out = (float*)d_out;
    float* cnt = (float*)d_ws;

    hipMemsetAsync(d_out, 0, (size_t)NNODE * 64 * sizeof(float), stream);
    hipMemsetAsync(d_ws,  0, (size_t)NNODE * sizeof(float), stream);
    nti_main<<<512, 512, 0, stream>>>(x_cen, x_nei, eidx, ln_g, ln_b,
                                      Wq, bq, Wk, bk, Wv, bv, Wo, bo, out, cnt);
    nti_div<<<(NNODE * 64 + 255) / 256, 256, 0, stream>>>(out, cnt);
}

// Round 14
// 266.132 us; speedup vs baseline: 1.0288x; 1.0288x over previous
//
#include <hip/hip_runtime.h>
#include <hip/hip_bf16.h>

#define NEDGE 800000
#define NNODE 50000
#define NBATCH (NEDGE / 128)   // 6250 batches of 128 edges (8 waves x 16 edges)

typedef __attribute__((ext_vector_type(8))) short bf16x8;
typedef __attribute__((ext_vector_type(4))) float f32x4;
typedef __attribute__((ext_vector_type(4))) float f4;

static __device__ __forceinline__ unsigned short f2bf(float f) {
    union { float f; unsigned u; } v; v.f = f;
    unsigned r = v.u + 0x7fffu + ((v.u >> 16) & 1u);   // RNE
    return (unsigned short)(r >> 16);
}

// DPP-based sum allreduce over each 16-lane quarter (DPP "row" = 16 lanes).
template<int CTRL>
static __device__ __forceinline__ float dppadd(float x) {
    int y = __builtin_amdgcn_update_dpp(0, __builtin_bit_cast(int, x), CTRL, 0xf, 0xf, true);
    return x + __builtin_bit_cast(float, y);
}
static __device__ __forceinline__ float allred16(float x) {
    x = dppadd<0xB1>(x);    // quad_perm xor1
    x = dppadd<0x4E>(x);    // quad_perm xor2
    x = dppadd<0x141>(x);   // row_half_mirror
    x = dppadd<0x140>(x);   // row_mirror
    return x;
}

static __device__ __forceinline__ unsigned cvt_pk_bf16(float lo, float hi) {
    unsigned r;
    asm("v_cvt_pk_bf16_f32 %0, %1, %2" : "=v"(r) : "v"(lo), "v"(hi));
    return r;
}
// raw 2^x (scores pre-scaled by log2e folded into Wq/bq); |x| < ~16 here
static __device__ __forceinline__ float fexp2(float x) {
    float r; asm("v_exp_f32 %0, %1" : "=v"(r) : "v"(x)); return r;
}

// LESSON (R9): Wo cannot fold into Wv (multi-head). LESSON (R11): hand-folded
// byte-offset loads failed correctness. LESSON (R13): Q-tile dedup regressed
// (extra serial LN outweighs 24 saved MFMAs).
// LAUNCH_BOUNDS DISCOVERY (R14): hipcc's 2nd arg behaves as min BLOCKS/CU:
// (512,4)->64 VGPR cap, (512,6)->40 (=512/(2*arg)). Residency is 2 blocks/CU
// (grid=512), so the correct bound is (512,2) = 128-reg budget. R3's spill
// was the 42-reg cap, not 85.
__global__ __launch_bounds__(512, 2) void nti_main(
    const float* __restrict__ x_cen, const float* __restrict__ x_nei,
    const int* __restrict__ eidx,
    const float* __restrict__ ln_g, const float* __restrict__ ln_b,
    const float* __restrict__ Wq, const float* __restrict__ bq,
    const float* __restrict__ Wk, const float* __restrict__ bk,
    const float* __restrict__ Wv, const float* __restrict__ bv,
    const float* __restrict__ Wo, const float* __restrict__ bo,
    float* __restrict__ outsum, float* __restrict__ cnt)
{
    // B-fragments: [mat*8 + kh*4 + nt][lane][8 bf16]  (q=0,k=1,v=2,o=3)
    __shared__ __align__(16) unsigned short wfrag[32][64][8];   // 32 KB
    __shared__ float bias_s[4][64];                             // 1 KB
    // per-wave O tile: 16 rows (edges) x 64 cols, pad to 72 (row = 144B)
    __shared__ __align__(16) unsigned short obuf[8][16][72];    // 18 KB

    const int tid = threadIdx.x;

    // ---- one-time weight staging: fold LN affine into Wq/Wk/Wv; fold
    // D^-0.5 * log2(e) into Wq/bq so softmax uses raw v_exp_f32 (2^x) ----
    if (tid < 256) {
        const int mat = tid >> 6, c = tid & 63;
        const float* W  = (mat == 0) ? Wq : (mat == 1) ? Wk : (mat == 2) ? Wv : Wo;
        const float* bb = (mat == 0) ? bq : (mat == 1) ? bk : (mat == 2) ? bv : bo;
        const float qs = (mat == 0) ? 0.25f * 1.44269504f : 1.0f;
        float bias = bb[c];
        for (int j = 0; j < 64; ++j) {
            float w = W[c * 64 + j];
            if (mat < 3) { bias += ln_b[j] * w; w *= ln_g[j]; }
            const int kh = j >> 5, ln = ((j >> 3) & 3) * 16 + (c & 15), i = j & 7;
            wfrag[mat * 8 + kh * 4 + (c >> 4)][ln][i] = f2bf(w * qs);
        }
        bias_s[mat][c] = bias * qs;
    }
    __syncthreads();

    const int wid = tid >> 6, lane = tid & 63;
    const int qg = lane >> 4;        // quarter / k-chunk
    const int rt = lane & 15;        // row within M-tile
    const int tok = rt & 3;          // token type of this row
    const int em  = rt >> 2;         // edge within M-tile
    const float ac = (tok == 0 || tok == 2) ? 1.f : (tok == 3) ? -1.f : 0.f;
    const float an = (tok == 0) ? 0.f : 1.f;

    // loop-invariant biases -> registers (bk dropped: softmax shift-invariant;
    // bv post-added since sum attn = 1; bo folded into residual add)
    float biasq[4], biasv[4], biaso[4];
    #pragma unroll
    for (int nt = 0; nt < 4; ++nt) {
        biasq[nt] = bias_s[0][nt * 16 + rt];
        biasv[nt] = bias_s[2][nt * 16 + rt];
        biaso[nt] = bias_s[3][nt * 16 + rt];
    }
    const f32x4 vzero = {0.f, 0.f, 0.f, 0.f};   // persistent zero C operand

    for (int batch = blockIdx.x; batch < NBATCH; batch += gridDim.x) {
        const int ebase = batch * 128 + wid * 16;

        // prefetch scatter targets early; pre-multiplied byte-offset bases so
        // epilogue atomics use base + imm-foldable nt*16
        int tg[4], tgb[4];
        #pragma unroll
        for (int r = 0; r < 4; ++r) {
            tg[r]  = eidx[NEDGE + ebase + qg * 4 + r];
            tgb[r] = tg[r] * 64 + rt;
        }

        // ---- phase 1: build A-fragments (LN'd tokens) for 4 M-tiles = 16 edges ----
        bf16x8 af[4][2];
        #pragma unroll
        for (int m = 0; m < 4; ++m) {
            const int eg = ebase + m * 4 + em;            // int32 offsets throughout
            const f4* pc4 = (const f4*)(x_cen + eg * 64);
            const f4* pn4 = (const f4*)(x_nei + eg * 64);
            f4 a0 = pc4[qg * 2], a1 = pc4[qg * 2 + 1], a2 = pc4[8 + qg * 2], a3 = pc4[8 + qg * 2 + 1];
            f4 b0 = pn4[qg * 2], b1 = pn4[qg * 2 + 1], b2 = pn4[8 + qg * 2], b3 = pn4[8 + qg * 2 + 1];
            float tv[16];
            #pragma unroll
            for (int i = 0; i < 4; ++i) {
                tv[i]      = ac * a0[i] + an * b0[i];
                tv[4 + i]  = ac * a1[i] + an * b1[i];
                tv[8 + i]  = ac * a2[i] + an * b2[i];
                tv[12 + i] = ac * a3[i] + an * b3[i];
            }
            float s = 0.f, ss = 0.f;
            #pragma unroll
            for (int i = 0; i < 16; ++i) { s += tv[i]; ss = fmaf(tv[i], tv[i], ss); }
            s  += __shfl_xor(s, 16, 64);  ss += __shfl_xor(ss, 16, 64);
            s  += __shfl_xor(s, 32, 64);  ss += __shfl_xor(ss, 32, 64);
            const float mu  = s * 0.015625f;
            const float var = fmaf(ss, 0.015625f, -mu * mu);
            const float rs  = rsqrtf(var + 1e-5f);
            const float nmrs = -mu * rs;
            #pragma unroll
            for (int kh = 0; kh < 2; ++kh) {
                union { bf16x8 v; unsigned u[4]; } pk;
                #pragma unroll
                for (int p = 0; p < 4; ++p) {
                    float lo = fmaf(tv[kh * 8 + 2 * p],     rs, nmrs);
                    float hi = fmaf(tv[kh * 8 + 2 * p + 1], rs, nmrs);
                    pk.u[p] = cvt_pk_bf16(lo, hi);
                }
                af[m][kh] = pk.v;
            }
        }

        __builtin_amdgcn_s_setprio(1);   // MFMA/VALU-dense region; waves independent

        // ---- phase 2: per head nt: q/k/v proj + per-head softmax + PV ----
        #pragma unroll
        for (int nt = 0; nt < 4; ++nt) {
            bf16x8 wq0 = *(const bf16x8*)&wfrag[0  + nt][lane][0];
            bf16x8 wq1 = *(const bf16x8*)&wfrag[4  + nt][lane][0];
            bf16x8 wk0 = *(const bf16x8*)&wfrag[8  + nt][lane][0];
            bf16x8 wk1 = *(const bf16x8*)&wfrag[12 + nt][lane][0];
            bf16x8 wv0 = *(const bf16x8*)&wfrag[16 + nt][lane][0];
            bf16x8 wv1 = *(const bf16x8*)&wfrag[20 + nt][lane][0];
            #pragma unroll
            for (int m = 0; m < 4; ++m) {
                f32x4 aq = __builtin_amdgcn_mfma_f32_16x16x32_bf16(af[m][0], wq0, vzero, 0, 0, 0);
                aq = __builtin_amdgcn_mfma_f32_16x16x32_bf16(af[m][1], wq1, aq, 0, 0, 0);
                f32x4 ak = __builtin_amdgcn_mfma_f32_16x16x32_bf16(af[m][0], wk0, vzero, 0, 0, 0);
                ak = __builtin_amdgcn_mfma_f32_16x16x32_bf16(af[m][1], wk1, ak, 0, 0, 0);
                f32x4 av = __builtin_amdgcn_mfma_f32_16x16x32_bf16(af[m][0], wv0, vzero, 0, 0, 0);
                av = __builtin_amdgcn_mfma_f32_16x16x32_bf16(af[m][1], wv1, av, 0, 0, 0);
                // scores: q row (reg 0 = edge m*4+qg token 0) dot k rows over
                // this head's 16 dims (= the 16 rt lanes of quarter qg)
                const float q0 = aq[0] + biasq[nt];
                float p0 = allred16(q0 * ak[0]);
                float p1 = allred16(q0 * ak[1]);
                float p2 = allred16(q0 * ak[2]);
                float p3 = allred16(q0 * ak[3]);
                // softmax: no max-sub (|p| bounded); log2e pre-folded -> raw 2^x
                const float e0 = fexp2(p0), e1 = fexp2(p1);
                const float e2 = fexp2(p2), e3 = fexp2(p3);
                const float inv = __builtin_amdgcn_rcpf(e0 + e1 + e2 + e3);
                const float dot = e0 * av[0] + e1 * av[1] + e2 * av[2] + e3 * av[3];
                const float ov = fmaf(dot, inv, biasv[nt]);   // bv post-add (sum attn = 1)
                obuf[wid][m * 4 + qg][nt * 16 + rt] = (unsigned short)cvt_pk_bf16(ov, ov);
            }
        }
        // no __syncthreads: obuf is per-wave; same-wave LDS RAW is lgkmcnt-ordered

        // ---- residual prefetch (+bo fold): overlap L2 latency with phase-3 ----
        float res[4][4];
        #pragma unroll
        for (int nt = 0; nt < 4; ++nt) {
            const int col = nt * 16 + rt;
            #pragma unroll
            for (int r = 0; r < 4; ++r)
                res[nt][r] = x_cen[(ebase + qg * 4 + r) * 64 + col] + biaso[nt];
        }

        // ---- phase 3: Wo projection (all 16 rows = 16 edges valid) ----
        bf16x8 oa0 = *(const bf16x8*)&obuf[wid][rt][qg * 8];
        bf16x8 oa1 = *(const bf16x8*)&obuf[wid][rt][32 + qg * 8];
        f32x4 accO[4];
        #pragma unroll
        for (int nt = 0; nt < 4; ++nt) {
            bf16x8 wo0 = *(const bf16x8*)&wfrag[24 + nt][lane][0];
            bf16x8 wo1 = *(const bf16x8*)&wfrag[28 + nt][lane][0];
            f32x4 acc = __builtin_amdgcn_mfma_f32_16x16x32_bf16(oa0, wo0, vzero, 0, 0, 0);
            acc = __builtin_amdgcn_mfma_f32_16x16x32_bf16(oa1, wo1, acc, 0, 0, 0);
            accO[nt] = acc;
        }
        __builtin_amdgcn_s_setprio(0);

        // ---- epilogue: residual + scatter-add (all 64 lanes active) ----
        #pragma unroll
        for (int nt = 0; nt < 4; ++nt) {
            #pragma unroll
            for (int r = 0; r < 4; ++r) {
                const float val = accO[nt][r] + res[nt][r];
                atomicAdd(outsum + tgb[r] + nt * 16, val);
            }
        }
        if (rt == 0) {
            #pragma unroll
            for (int r = 0; r < 4; ++r) atomicAdd(cnt + tg[r], 1.0f);
        }
    }
}

__global__ void nti_div(float* __restrict__ out, const float* __restrict__ cnt) {
    int i = blockIdx.x * 256 + threadIdx.x;
    if (i < NNODE * 64) {
        float c = cnt[i >> 6];
        out[i] = out[i] / fmaxf(c, 1.0f);
    }
}

extern "C" void kernel_launch(void* const* d_in, const int* in_sizes, int n_in,
                              void* d_out, int out_size, void* d_ws, size_t ws_size,
                              hipStream_t stream) {
    const float* x_cen = (const float*)d_in[0];
    const float* x_nei = (const float*)d_in[1];
    const int*   eidx  = (const int*)d_in[2];
    const float* ln_g  = (const float*)d_in[3];
    const float* ln_b  = (const float*)d_in[4];
    const float* Wq = (const float*)d_in[5];  const float* bq = (const float*)d_in[6];
    const float* Wk = (const float*)d_in[7];  const float* bk = (const float*)d_in[8];
    const float* Wv = (const float*)d_in[9];  const float* bv = (const float*)d_in[10];
    const float* Wo = (const float*)d_in[11]; const float* bo = (const float*)d_in[12];
    float* out = (float*)d_out;
    float* cnt = (float*)d_ws;

    hipMemsetAsync(d_out, 0, (size_t)NNODE * 64 * sizeof(float), stream);
    hipMemsetAsync(d_ws,  0, (size_t)NNODE * sizeof(float), stream);
    nti_main<<<512, 512, 0, stream>>>(x_cen, x_nei, eidx, ln_g, ln_b,
                                      Wq, bq, Wk, bk, Wv, bv, Wo, bo, out, cnt);
    nti_div<<<(NNODE * 64 + 255) / 256, 256, 0, stream>>>(out, cnt);
}